// Round 10
// baseline (321.117 us; speedup 1.0000x reference)
//
#include <hip/hip_runtime.h>
#include <hip/hip_bf16.h>

// Hopfield sparsemax attention, MI355X gfx950.
// B=1, L=S=2048, D_MODEL=1024, H=16, DK=64. Inputs fp32 (runtime-detected), output per flag.
//
// Round-10:
//   0.  detect dtype -> flag
//   p1. Qc/Kc = bf16(queries/keys)        [2048,1024]
//   p2. W*T = bf16(W^T)                   [1024,1024] x4 (LDS-tiled transpose)
//   1.  {Qb,Kb} projections batched via grid.z (64-tile GEMM w/ global_load_lds)
//   2.  Vb = Kb @ WvT + bv                (ref quirk: V from key projection)
//   3.  attn_fused v4: ONE WAVE per (16 Q-rows x head). No K staging, no barriers:
//       B-frags stream from global (L2), pass1 = per-lane reg max -> exact row max,
//       pass2 = append candidates z >= M-1 (exact sparsemax-support superset) to
//       per-wave LDS lists (fp32 val + u16 idx, CAP 208). Michelot -> exact tau;
//       ballot-compact; 8-deep sparse PV gather. Scores never reach HBM.
//   4.  out = Ob @ WoT + bo

typedef __attribute__((ext_vector_type(8))) short short8;
typedef __attribute__((ext_vector_type(4))) float floatx4;

#define SRC_BF16 0
#define SRC_F32  1
#define SRC_RT   2
#define CAP 208

__device__ __forceinline__ short f2bf(float f) {
    __hip_bfloat16 h = __float2bfloat16(f);
    return *reinterpret_cast<const short*>(&h);
}
__device__ __forceinline__ float bf2f(unsigned short u) {
    return __uint_as_float(((unsigned)u) << 16);
}

// async 16B global -> LDS (wave-uniform LDS base; HW scatters lane*16)
__device__ __forceinline__ void async_cp16(const void* g, void* l) {
    __builtin_amdgcn_global_load_lds(
        (const __attribute__((address_space(1))) void*)g,
        (__attribute__((address_space(3))) void*)l, 16, 0, 0);
}

// Detect input dtype: decode first n shorts as bf16; fp32-read-as-bf16 almost surely
// yields |x|>1e10 / inf / NaN. One 64-thread block.
__global__ void detect_k(const short* __restrict__ q, int n, int* __restrict__ flag)
{
    const int tid = threadIdx.x;
    int bad = 0;
    for (int i = tid; i < n; i += 64) {
        float f = bf2f((unsigned short)q[i]);
        if (!(fabsf(f) < 1e10f)) bad = 1;
    }
    unsigned long long m = __ballot(bad != 0);
    if (tid == 0) *flag = (m != 0ULL) ? 1 : 0;
}

// Flat convert (fp32|bf16 per flag) -> bf16. z selects one of two sources.
__global__ __launch_bounds__(256)
void convert2_k(const void* __restrict__ s0, const void* __restrict__ s1,
                short* __restrict__ d0, short* __restrict__ d1,
                const int* __restrict__ dflag)
{
    const void* s = blockIdx.z ? s1 : s0;
    short* d = blockIdx.z ? d1 : d0;
    const size_t i = ((size_t)blockIdx.x * 256 + threadIdx.x) * 8;
    short8 o;
    if (*dflag) {
        const float4 f0 = ((const float4*)((const float*)s + i))[0];
        const float4 f1 = ((const float4*)((const float*)s + i))[1];
        o[0] = f2bf(f0.x); o[1] = f2bf(f0.y); o[2] = f2bf(f0.z); o[3] = f2bf(f0.w);
        o[4] = f2bf(f1.x); o[5] = f2bf(f1.y); o[6] = f2bf(f1.z); o[7] = f2bf(f1.w);
    } else {
        o = *(const short8*)((const short*)s + i);
    }
    *(short8*)(d + i) = o;
}

// Batched weight transpose: 4 matrices [R,C] -> bf16 [C,R], selected by blockIdx.z.
struct TP4 {
    const void* s[4];
    short* d[4];
};
__global__ __launch_bounds__(256)
void transpose4_k(TP4 p, int R, int C, const int* __restrict__ dflag)
{
    __shared__ short T[64][72];
    const int tid = threadIdx.x;
    const int bC = blockIdx.x, bR = blockIdx.y;
    const void* src = p.s[blockIdx.z];
    short* dst = p.d[blockIdx.z];
    const bool f32 = (*dflag != 0);

    const int colg = (tid & 7) * 8;
    #pragma unroll
    for (int h = 0; h < 2; ++h) {
        const int row = (tid >> 3) + 32 * h;
        const size_t idx = (size_t)(bR * 64 + row) * (size_t)C + (size_t)(bC * 64 + colg);
        short e[8];
        if (f32) {
            const float4 f0 = ((const float4*)((const float*)src + idx))[0];
            const float4 f1 = ((const float4*)((const float*)src + idx))[1];
            e[0] = f2bf(f0.x); e[1] = f2bf(f0.y); e[2] = f2bf(f0.z); e[3] = f2bf(f0.w);
            e[4] = f2bf(f1.x); e[5] = f2bf(f1.y); e[6] = f2bf(f1.z); e[7] = f2bf(f1.w);
        } else {
            short8 s = *(const short8*)((const short*)src + idx);
            #pragma unroll
            for (int j = 0; j < 8; ++j) e[j] = s[j];
        }
        #pragma unroll
        for (int j = 0; j < 8; ++j) T[colg + j][row] = e[j];
    }
    __syncthreads();
    #pragma unroll
    for (int h = 0; h < 2; ++h) {
        const int orow = (tid >> 3) + 32 * h;
        const int ocolg = (tid & 7) * 8;
        const size_t idx = (size_t)(bC * 64 + orow) * (size_t)R + (size_t)(bR * 64 + ocolg);
        *(short8*)(dst + idx) = *(const short8*)&T[orow][ocolg];
    }
}

// ---------------- 64x64-tile GEMM, bf16 A [2048,1024] x bf16 Bt [1024,1024] ----------
// C = A@Bt^T + bias. Staging via global_load_lds width=16 into UNPADDED [64][32] LDS:
// wave w lane l writes flat byte 1024w + 16l == As[16w + (l>>2)][(l&3)*8] -- exactly the
// wave-uniform-base + lane*16 contract. Fragment ds_reads hit 64 distinct 16B chunks
// (conflict-free). Two jobs selectable via blockIdx.z.
struct GJ { const short* A; const short* B; const void* bias; void* C; };

template<int OSRC>
__global__ __launch_bounds__(256)
void gemm64_bt_k(GJ j0, GJ j1, const int* __restrict__ dflag)
{
    __shared__ __align__(16) short AsF[64 * 32];
    __shared__ __align__(16) short BsF[64 * 32];

    const GJ j = blockIdx.z ? j1 : j0;
    const int rtf = *dflag;

    const int tid  = threadIdx.x;
    const int bN   = blockIdx.x, bM = blockIdx.y;
    const int lane = tid & 63, wave = tid >> 6;
    const int wm   = (wave >> 1) * 32;
    const int wn   = (wave & 1) * 32;
    const int quad = lane >> 4, r16 = lane & 15;

    floatx4 acc[2][2];
    #pragma unroll
    for (int i = 0; i < 2; ++i)
        #pragma unroll
        for (int jj = 0; jj < 2; ++jj)
            acc[i][jj] = (floatx4){0.f, 0.f, 0.f, 0.f};

    const int srow = tid >> 2, scol = (tid & 3) * 8;
    const short* ga = j.A + (size_t)(bM * 64 + srow) * 1024 + scol;
    const short* gb = j.B + (size_t)(bN * 64 + srow) * 1024 + scol;
    short* ldsA = AsF + 512 * wave;   // wave-uniform base
    short* ldsB = BsF + 512 * wave;

    for (int k0 = 0; k0 < 1024; k0 += 32) {
        async_cp16(ga, ldsA);
        async_cp16(gb, ldsB);
        ga += 32; gb += 32;
        __syncthreads();   // drains vmcnt (global_load_lds) before ds_read

        short8 a0 = *(const short8*)&AsF[(wm + r16) * 32 + quad * 8];
        short8 a1 = *(const short8*)&AsF[(wm + 16 + r16) * 32 + quad * 8];
        short8 b0 = *(const short8*)&BsF[(wn + r16) * 32 + quad * 8];
        short8 b1 = *(const short8*)&BsF[(wn + 16 + r16) * 32 + quad * 8];

        acc[0][0] = __builtin_amdgcn_mfma_f32_16x16x32_bf16(a0, b0, acc[0][0], 0, 0, 0);
        acc[0][1] = __builtin_amdgcn_mfma_f32_16x16x32_bf16(a0, b1, acc[0][1], 0, 0, 0);
        acc[1][0] = __builtin_amdgcn_mfma_f32_16x16x32_bf16(a1, b0, acc[1][0], 0, 0, 0);
        acc[1][1] = __builtin_amdgcn_mfma_f32_16x16x32_bf16(a1, b1, acc[1][1], 0, 0, 0);
        __syncthreads();
    }

    const bool of32 = (OSRC == SRC_F32) || (OSRC == SRC_RT && rtf);
    #pragma unroll
    for (int jj = 0; jj < 2; ++jj) {
        const int gc = bN * 64 + wn + jj * 16 + r16;
        const float bb = rtf ? ((const float*)j.bias)[gc]
                             : bf2f(((const unsigned short*)j.bias)[gc]);
        #pragma unroll
        for (int i = 0; i < 2; ++i) {
            #pragma unroll
            for (int rg = 0; rg < 4; ++rg) {
                const int gr = bM * 64 + wm + i * 16 + quad * 4 + rg;
                const float v = acc[i][jj][rg] + bb;
                if (of32)
                    ((float*)j.C)[(size_t)gr * 1024 + gc] = v;
                else
                    ((__hip_bfloat16*)j.C)[(size_t)gr * 1024 + gc] = __float2bfloat16(v);
            }
        }
    }
}

// ---------------- fused attention v4: one wave per (16 Q-rows, head) ----------------
// No K LDS staging, no barriers. B-fragments load directly from global (L2-served;
// 16 fully-used 128B lines per 16-col tile). Pass 1: per-lane register max (4 fmax per
// tile), one 4-shuffle fold at the end -> EXACT row max. Pass 2: recompute scores,
// append candidates z >= M-1 (superset of sparsemax support: z > tau >= M-1) into
// per-wave LDS lists, fp32 values. Michelot -> exact tau. Ballot-compact support,
// 8-deep unrolled sparse PV gather (V rows are single 128B lines, coalesced by lane).
__global__ __launch_bounds__(64)
void attn_fused_k(const short* __restrict__ Qb, const short* __restrict__ Kb,
                  const short* __restrict__ Vb, short* __restrict__ Ob)
{
    __shared__ float cval[16][CAP];
    __shared__ unsigned short cidx[16][CAP];
    __shared__ int cnt[16];

    const int lane = threadIdx.x;          // single wave
    const int quad = lane >> 4, r16 = lane & 15;
    const int r0 = blockIdx.x * 16;
    const int h  = blockIdx.y;

    if (lane < 16) cnt[lane] = 0;

    // A fragments: Q rows r0..r0+15 (m = r16), direct from global
    const short* qp = Qb + (size_t)(r0 + r16) * 1024 + h * 64;
    const short8 a0 = *(const short8*)(qp + quad * 8);
    const short8 a1 = *(const short8*)(qp + 32 + quad * 8);

    const short* kb = Kb + h * 64;

    // ---- pass 1: per-lane running max (unscaled) ----
    float mx[4] = {-3.0e38f, -3.0e38f, -3.0e38f, -3.0e38f};
    for (int c0 = 0; c0 < 2048; c0 += 64) {
        floatx4 acc[4];
        #pragma unroll
        for (int t = 0; t < 4; ++t) {
            const short* kp = kb + (size_t)(c0 + t * 16 + r16) * 1024;
            const short8 b0 = *(const short8*)(kp + quad * 8);
            const short8 b1 = *(const short8*)(kp + 32 + quad * 8);
            floatx4 a = (floatx4){0.f, 0.f, 0.f, 0.f};
            a = __builtin_amdgcn_mfma_f32_16x16x32_bf16(a0, b0, a, 0, 0, 0);
            a = __builtin_amdgcn_mfma_f32_16x16x32_bf16(a1, b1, a, 0, 0, 0);
            acc[t] = a;
        }
        #pragma unroll
        for (int t = 0; t < 4; ++t)
            #pragma unroll
            for (int rg = 0; rg < 4; ++rg)
                mx[rg] = fmaxf(mx[rg], acc[t][rg]);
    }
    // fold over r16 (bits 0..3): every lane of a quad gets its 4 rows' exact maxes
    #pragma unroll
    for (int off = 1; off < 16; off <<= 1)
        #pragma unroll
        for (int rg = 0; rg < 4; ++rg)
            mx[rg] = fmaxf(mx[rg], __shfl_xor(mx[rg], off, 64));
    float thr[4];
    #pragma unroll
    for (int rg = 0; rg < 4; ++rg) thr[rg] = mx[rg] * 0.125f - 1.0f;

    // ---- pass 2: recompute, append candidates >= M-1 ----
    for (int c0 = 0; c0 < 2048; c0 += 64) {
        floatx4 acc[4];
        #pragma unroll
        for (int t = 0; t < 4; ++t) {
            const short* kp = kb + (size_t)(c0 + t * 16 + r16) * 1024;
            const short8 b0 = *(const short8*)(kp + quad * 8);
            const short8 b1 = *(const short8*)(kp + 32 + quad * 8);
            floatx4 a = (floatx4){0.f, 0.f, 0.f, 0.f};
            a = __builtin_amdgcn_mfma_f32_16x16x32_bf16(a0, b0, a, 0, 0, 0);
            a = __builtin_amdgcn_mfma_f32_16x16x32_bf16(a1, b1, a, 0, 0, 0);
            acc[t] = a;
        }
        #pragma unroll
        for (int t = 0; t < 4; ++t) {
            #pragma unroll
            for (int rg = 0; rg < 4; ++rg) {
                const float val = acc[t][rg] * 0.125f;
                if (val >= thr[rg]) {
                    const int row = quad * 4 + rg;
                    const int p = atomicAdd(&cnt[row], 1);
                    if (p < CAP) {
                        cval[row][p] = val;
                        cidx[row][p] = (unsigned short)(c0 + t * 16 + r16);
                    }
                }
            }
        }
    }
    __syncthreads();   // single-wave: compiles to waitcnt; orders LDS for epilogue

    // ---- per-row Michelot + sparse PV ----
    const unsigned long long pre = (1ULL << lane) - 1ULL;
    const unsigned short* vb = (const unsigned short*)Vb + h * 64 + lane;  // lane = out col

    for (int rr = 0; rr < 16; ++rr) {
        const int n = min(cnt[rr], CAP);

        float v[4];
        unsigned short ii[4];
        #pragma unroll
        for (int i = 0; i < 4; ++i) {
            const int ix = lane + i * 64;
            if (ix < n) { v[i] = cval[rr][ix]; ii[i] = cidx[rr][ix]; }
            else        { v[i] = -3.0e38f;     ii[i] = 0; }
        }

        float tau = -3.0e38f, prevc = -1.0f;
        for (int it = 0; it < 24; ++it) {
            float s = 0.f, c = 0.f;
            #pragma unroll
            for (int i = 0; i < 4; ++i)
                if (v[i] > tau) { s += v[i]; c += 1.f; }
            #pragma unroll
            for (int off = 1; off < 64; off <<= 1) {
                s += __shfl_xor(s, off, 64);
                c += __shfl_xor(c, off, 64);
            }
            if (c == prevc) break;
            prevc = c;
            tau = (s - 1.0f) / c;
        }

        // ballot-compact support (p = v - tau > 0) to list front, fp32 p
        int base = 0;
        #pragma unroll
        for (int i = 0; i < 4; ++i) {
            const float p = v[i] - tau;
            const unsigned long long m = __ballot(p > 0.f);
            const int w = base + __popcll(m & pre);
            if (p > 0.f) { cval[rr][w] = p; cidx[rr][w] = ii[i]; }
            base += __popcll(m);
        }
        const int msup = base;

        // sparse PV gather: 8-deep independent loads
        float av[8] = {0.f, 0.f, 0.f, 0.f, 0.f, 0.f, 0.f, 0.f};
        int jj = 0;
        for (; jj + 8 <= msup; jj += 8) {
            #pragma unroll
            for (int u = 0; u < 8; ++u) {
                const float p = cval[rr][jj + u];
                const int ki = cidx[rr][jj + u];
                av[u] += p * bf2f(vb[(size_t)ki * 1024]);
            }
        }
        for (; jj < msup; ++jj)
            av[0] += cval[rr][jj] * bf2f(vb[(size_t)cidx[rr][jj] * 1024]);

        const float s = ((av[0] + av[1]) + (av[2] + av[3]))
                      + ((av[4] + av[5]) + (av[6] + av[7]));
        Ob[((size_t)h * 2048 + r0 + rr) * 64 + lane] = f2bf(s);
    }
}

extern "C" void kernel_launch(void* const* d_in, const int* in_sizes, int n_in,
                              void* d_out, int out_size, void* d_ws, size_t ws_size,
                              hipStream_t stream)
{
    (void)in_sizes; (void)n_in; (void)out_size; (void)ws_size;

    const void* queries = d_in[0];
    const void* keys    = d_in[1];
    // d_in[2] ("values") unused by the reference.
    const void* Wq = d_in[3];
    const void* bq = d_in[4];
    const void* Wk = d_in[5];
    const void* bk = d_in[6];
    const void* Wv = d_in[7];
    const void* bv = d_in[8];
    const void* Wo = d_in[9];
    const void* bo = d_in[10];

    const int L = 2048, DM = 1024;
    const size_t LD = (size_t)L * DM;   // 2M elements

    int*   flag = (int*)d_ws;
    short* Qc  = (short*)((char*)d_ws + 256);  // bf16 queries      [2048,1024]
    short* Kc  = Qc + LD;                      // bf16 keys         [2048,1024]
    short* WqT = Kc + LD;                      // bf16 Wq^T         [1024,1024]
    short* WkT = WqT + (size_t)DM * DM;
    short* WvT = WkT + (size_t)DM * DM;
    short* WoT = WvT + (size_t)DM * DM;
    short* Qb  = WoT + (size_t)DM * DM;        // [2048,1024]
    short* Kb  = Qb + LD;
    short* Vb  = Kb + LD;
    short* Ob  = Vb + LD;                      // [H,2048,64] contiguous (== mixed view)

    dim3 blk(256);

    // 0) dtype detection
    detect_k<<<dim3(1), dim3(64), 0, stream>>>((const short*)queries, 4096, flag);

    // p1) convert queries/keys -> bf16
    convert2_k<<<dim3((unsigned)(LD / 2048), 1, 2), blk, 0, stream>>>(
        queries, keys, Qc, Kc, flag);

    // p2) transpose-convert the 4 weight matrices -> bf16 [N][K]
    {
        TP4 p;
        p.s[0] = Wq; p.s[1] = Wk; p.s[2] = Wv; p.s[3] = Wo;
        p.d[0] = WqT; p.d[1] = WkT; p.d[2] = WvT; p.d[3] = WoT;
        transpose4_k<<<dim3(DM / 64, DM / 64, 4), blk, 0, stream>>>(p, DM, DM, flag);
    }

    // 1) Qb & Kb projections batched (1024 blocks = 4/CU)
    {
        GJ jq{(const short*)Qc, WqT, bq, Qb};
        GJ jk{(const short*)Kc, WkT, bk, Kb};
        gemm64_bt_k<SRC_BF16><<<dim3(DM / 64, L / 64, 2), blk, 0, stream>>>(jq, jk, flag);
    }
    // 2) Vb = Kb @ WvT + bv   (reference quirk: V from key projection)
    {
        GJ jv{(const short*)Kb, WvT, bv, Vb};
        gemm64_bt_k<SRC_BF16><<<dim3(DM / 64, L / 64, 1), blk, 0, stream>>>(jv, jv, flag);
    }

    // 3) fused attention: one wave per (16 rows, head); scores never reach HBM
    attn_fused_k<<<dim3(L / 16, 16), dim3(64), 0, stream>>>(Qb, Kb, Vb, Ob);

    // 4) out = Ob(viewed [2048,1024]) @ WoT + bo -> d_out (dtype per flag)
    {
        GJ jo{(const short*)Ob, WoT, bo, d_out};
        gemm64_bt_k<SRC_RT><<<dim3(DM / 64, L / 64, 1), blk, 0, stream>>>(jo, jo, flag);
    }
}